// Round 5
// baseline (353.099 us; speedup 1.0000x reference)
//
#include <hip/hip_runtime.h>
#include <cstddef>
#include <cstdint>

#define BSZ   4
#define SEQ   4096
#define DIN   1024
#define HDIM  1024
#define MTOT  (BSZ * SEQ)            // 16384 rows
#define NELE  ((size_t)MTOT * HDIM)  // 16.7M elements per [bs,S,H] tensor
#define NX    ((size_t)MTOT * DIN)   // x elements
#define NW    ((size_t)HDIM * DIN)   // per-weight elements
#define NCH   64                     // scan chunks
#define CL    (SEQ / NCH)            // 64 steps per chunk

#define BM 128
#define BN 128
#define BK 32

#define X4 (NX / 4)                  // 4,194,304 float4s
#define W4 (NW / 4)                  // 262,144 float4s

using bf16x8 = __attribute__((ext_vector_type(8))) __bf16;
using f32x4  = __attribute__((ext_vector_type(4))) float;

// ---------- bf16 bit helpers ----------
__device__ __forceinline__ float bf2f(unsigned int u16bits) {
    union { unsigned int i; float f; } v;
    v.i = u16bits << 16;
    return v.f;
}
// round-half-up pack of two floats -> (lo=a, hi=b) bf16 pair
__device__ __forceinline__ unsigned int pk2(float a, float b) {
    union { float f; unsigned int i; } ua, ub; ua.f = a; ub.f = b;
    return ((ua.i + 0x8000u) >> 16) | ((ub.i + 0x8000u) & 0xffff0000u);
}

// async 16B global -> LDS (wave-uniform LDS base + lane*16)
__device__ __forceinline__ void gload16(const void* g, void* l) {
    __builtin_amdgcn_global_load_lds(
        (const __attribute__((address_space(1))) unsigned int*)g,
        (__attribute__((address_space(3))) unsigned int*)l, 16, 0, 0);
}

// ---------- fp32 -> bf16 pre-convert (x, Wz, Wh) ----------
__global__ __launch_bounds__(256) void cvt_bf16(
    const float* __restrict__ x, const float* __restrict__ wz,
    const float* __restrict__ wh, unsigned short* __restrict__ xb,
    unsigned short* __restrict__ zb, unsigned short* __restrict__ hb)
{
    const size_t i = (size_t)blockIdx.x * 256 + threadIdx.x;
    const float4* src; unsigned short* dst; size_t off;
    if (i < X4)            { src = (const float4*)x;  dst = xb; off = i; }
    else if (i < X4 + W4)  { src = (const float4*)wz; dst = zb; off = i - X4; }
    else                   { src = (const float4*)wh; dst = hb; off = i - X4 - W4; }
    const float4 v = src[off];
    uint2 r; r.x = pk2(v.x, v.y); r.y = pk2(v.z, v.w);
    ((uint2*)dst)[off] = r;
}

// ---------- MFMA GEMM + activation epilogue ----------
// ab[m*HDIM+n] = bf16pair( a = sigmoid(-k), b = sigmoid(k)*g(ph) )
__global__ __launch_bounds__(256) void gemm_act_mfma(
    const unsigned short* __restrict__ xb, const unsigned short* __restrict__ zb,
    const unsigned short* __restrict__ hb, const float* __restrict__ bz,
    const float* __restrict__ bh, unsigned int* __restrict__ ab)
{
    __shared__ unsigned short xs[BM * BK];   // 8 KB, row-major, 64 B/row, NO pad
    __shared__ unsigned short zs[BN * BK];
    __shared__ unsigned short hs[BN * BK];

    const int tid  = threadIdx.x;
    const int wid  = tid >> 6;
    const int lane = tid & 63;
    const int lm   = lane & 15;
    const int q    = lane >> 4;
    const int wy   = wid >> 1;   // wave m-half
    const int wx   = wid & 1;    // wave n-half

    const int m0 = blockIdx.y * BM;
    const int n0 = blockIdx.x * BN;

    // staging: wave wid covers rows wid*32 + j*16 + lane/4, byte-in-row (lane&3)*16
    const int srow  = wid * 32 + (lane >> 2);
    const int sbyte = (lane & 3) << 4;
    const char* gx = (const char*)xb + ((size_t)(m0 + srow) * DIN * 2 + sbyte);
    const char* gz = (const char*)zb + ((size_t)(n0 + srow) * DIN * 2 + sbyte);
    const char* gh = (const char*)hb + ((size_t)(n0 + srow) * DIN * 2 + sbyte);
    char* xl = (char*)xs + wid * 2048;
    char* zl = (char*)zs + wid * 2048;
    char* hl = (char*)hs + wid * 2048;
    const size_t rstep = (size_t)16 * DIN * 2;  // +16 rows in global

    f32x4 acc1[4][4], acc2[4][4];
#pragma unroll
    for (int mt = 0; mt < 4; ++mt)
#pragma unroll
        for (int nt = 0; nt < 4; ++nt) {
            acc1[mt][nt] = (f32x4){0.f, 0.f, 0.f, 0.f};
            acc2[mt][nt] = (f32x4){0.f, 0.f, 0.f, 0.f};
        }

    for (int k0 = 0; k0 < DIN; k0 += BK) {
        const size_t kb = (size_t)k0 * 2;
        __syncthreads();                       // previous tile consumed
        gload16(gx + kb,         xl);
        gload16(gx + kb + rstep, xl + 1024);
        gload16(gz + kb,         zl);
        gload16(gz + kb + rstep, zl + 1024);
        gload16(gh + kb,         hl);
        gload16(gh + kb + rstep, hl + 1024);
        __syncthreads();                       // drains vmcnt; tile visible

        bf16x8 a[4];
#pragma unroll
        for (int mt = 0; mt < 4; ++mt)
            a[mt] = *(const bf16x8*)((const char*)xs + ((wy * 64 + mt * 16 + lm) * 64 + q * 16));
#pragma unroll
        for (int nt = 0; nt < 4; ++nt) {
            const int bo = (wx * 64 + nt * 16 + lm) * 64 + q * 16;
            const bf16x8 vz = *(const bf16x8*)((const char*)zs + bo);
            const bf16x8 vh = *(const bf16x8*)((const char*)hs + bo);
#pragma unroll
            for (int mt = 0; mt < 4; ++mt) {
                acc1[mt][nt] = __builtin_amdgcn_mfma_f32_16x16x32_bf16(a[mt], vz, acc1[mt][nt], 0, 0, 0);
                acc2[mt][nt] = __builtin_amdgcn_mfma_f32_16x16x32_bf16(a[mt], vh, acc2[mt][nt], 0, 0, 0);
            }
        }
    }

    // epilogue: C layout col = lane&15, row = q*4 + r
#pragma unroll
    for (int mt = 0; mt < 4; ++mt) {
        const int row = m0 + wy * 64 + mt * 16 + q * 4;
#pragma unroll
        for (int nt = 0; nt < 4; ++nt) {
            const int col = n0 + wx * 64 + nt * 16 + lm;
            const float bzv = bz[col];
            const float bhv = bh[col];
#pragma unroll
            for (int r = 0; r < 4; ++r) {
                const float kpre = acc1[mt][nt][r] + bzv;
                const float hpre = acc2[mt][nt][r] + bhv;
                const float ez   = expf(-kpre);
                const float zv   = 1.0f / (1.0f + ez);   // sigmoid(k)
                const float av   = ez * zv;              // sigmoid(-k)
                const float g    = (hpre >= 0.0f) ? (hpre + 0.5f)
                                                  : (1.0f / (1.0f + expf(-hpre)));
                ab[(size_t)(row + r) * HDIM + col] = pk2(av, zv * g);
            }
        }
    }
}

// ---------- Phase A: per-chunk affine composition (A,B), 2 channels/thread ----------
__global__ __launch_bounds__(256) void scan_phaseA(
    const unsigned int* __restrict__ ab, float* __restrict__ carryA,
    float* __restrict__ carryB)
{
    const int h  = blockIdx.x * 512 + threadIdx.x * 2;
    const int c  = blockIdx.y;
    const int bi = blockIdx.z;
    size_t idx = ((size_t)bi * SEQ + (size_t)c * CL) * HDIM + h;
    float A0 = 1.f, B0 = 0.f, A1 = 1.f, B1 = 0.f;
#pragma unroll 4
    for (int t = 0; t < CL; ++t) {
        const uint2 v = *(const uint2*)&ab[idx];
        const float a0 = bf2f(v.x & 0xffffu), b0 = bf2f(v.x >> 16);
        const float a1 = bf2f(v.y & 0xffffu), b1 = bf2f(v.y >> 16);
        A0 *= a0; B0 = fmaf(a0, B0, b0);
        A1 *= a1; B1 = fmaf(a1, B1, b1);
        idx += HDIM;
    }
    const size_t ci = ((size_t)c * BSZ + bi) * HDIM + h;
    *(float2*)&carryA[ci] = make_float2(A0, A1);
    *(float2*)&carryB[ci] = make_float2(B0, B1);
}

// ---------- Phase B: sequential scan over chunk carries ----------
__global__ __launch_bounds__(256) void scan_phaseB(
    const float* __restrict__ h0, const float* __restrict__ carryA,
    const float* __restrict__ carryB, float* __restrict__ hin)
{
    const int h  = blockIdx.x * 256 + threadIdx.x;
    const int bi = blockIdx.y;
    const float v = h0[(size_t)bi * HDIM + h];
    float hr = (v >= 0.0f) ? (v + 0.5f) : (1.0f / (1.0f + expf(-v)));
    for (int c = 0; c < NCH; ++c) {
        const size_t ci = ((size_t)c * BSZ + bi) * HDIM + h;
        hin[ci] = hr;
        hr = fmaf(carryA[ci], hr, carryB[ci]);
    }
}

// ---------- Phase C: replay chunk with known h_in, write fp32 out ----------
__global__ __launch_bounds__(256) void scan_phaseC(
    const unsigned int* __restrict__ ab, const float* __restrict__ hin,
    float* __restrict__ out)
{
    const int h  = blockIdx.x * 512 + threadIdx.x * 2;
    const int c  = blockIdx.y;
    const int bi = blockIdx.z;
    size_t idx = ((size_t)bi * SEQ + (size_t)c * CL) * HDIM + h;
    const size_t ci = ((size_t)c * BSZ + bi) * HDIM + h;
    float2 hr = *(const float2*)&hin[ci];
#pragma unroll 4
    for (int t = 0; t < CL; ++t) {
        const uint2 v = *(const uint2*)&ab[idx];
        hr.x = fmaf(bf2f(v.x & 0xffffu), hr.x, bf2f(v.x >> 16));
        hr.y = fmaf(bf2f(v.y & 0xffffu), hr.y, bf2f(v.y >> 16));
        *(float2*)&out[idx] = hr;
        idx += HDIM;
    }
}

extern "C" void kernel_launch(void* const* d_in, const int* in_sizes, int n_in,
                              void* d_out, int out_size, void* d_ws, size_t ws_size,
                              hipStream_t stream)
{
    const float* x  = (const float*)d_in[0];
    const float* h0 = (const float*)d_in[1];
    const float* Wz = (const float*)d_in[2];
    const float* bz = (const float*)d_in[3];
    const float* Wh = (const float*)d_in[4];
    const float* bh = (const float*)d_in[5];
    float* out = (float*)d_out;

    // workspace layout (~108 MB total; known ws_size >= 137 MB)
    unsigned int*  ab  = (unsigned int*)d_ws;              // NELE uints (bf16 a,b pairs)
    unsigned short* xbf = (unsigned short*)(ab + NELE);    // NX
    unsigned short* zbf = xbf + NX;                        // NW
    unsigned short* hbf = zbf + NW;                        // NW
    float* carryA = (float*)(hbf + NW);
    float* carryB = carryA + (size_t)NCH * BSZ * HDIM;
    float* hin    = carryB + (size_t)NCH * BSZ * HDIM;

    const int cvtBlocks = (int)((X4 + 2 * W4) / 256);      // exact
    cvt_bf16<<<cvtBlocks, 256, 0, stream>>>(x, Wz, Wh, xbf, zbf, hbf);

    dim3 gGrid(HDIM / BN, MTOT / BM);                      // (8, 128)
    gemm_act_mfma<<<gGrid, 256, 0, stream>>>(xbf, zbf, hbf, bz, bh, ab);

    dim3 aGrid(HDIM / 512, NCH, BSZ);                      // (2, 64, 4)
    scan_phaseA<<<aGrid, 256, 0, stream>>>(ab, carryA, carryB);

    dim3 bGrid(HDIM / 256, BSZ);                           // (4, 4)
    scan_phaseB<<<bGrid, 256, 0, stream>>>(h0, carryA, carryB, hin);

    scan_phaseC<<<aGrid, 256, 0, stream>>>(ab, hin, out);
}

// Round 6
// 252.488 us; speedup vs baseline: 1.3985x; 1.3985x over previous
//
#include <hip/hip_runtime.h>
#include <cstddef>
#include <cstdint>

#define BSZ   4
#define SEQ   4096
#define DIN   1024
#define HDIM  1024
#define MTOT  (BSZ * SEQ)            // 16384 rows
#define NELE  ((size_t)MTOT * HDIM)
#define NX    ((size_t)MTOT * DIN)
#define NW    ((size_t)HDIM * DIN)
#define NCH   128                    // scan chunks (CL=32)
#define CL    (SEQ / NCH)

#define BM 128
#define BN 64
#define BK 32

#define X4 (NX / 4)
#define W4 (NW / 4)

using bf16x8 = __attribute__((ext_vector_type(8))) __bf16;
using f32x4  = __attribute__((ext_vector_type(4))) float;

// ---------- bf16 bit helpers ----------
__device__ __forceinline__ float bf2f(unsigned int u16bits) {
    union { unsigned int i; float f; } v;
    v.i = u16bits << 16;
    return v.f;
}
__device__ __forceinline__ unsigned int pk2(float a, float b) {  // (lo=a, hi=b)
    union { float f; unsigned int i; } ua, ub; ua.f = a; ub.f = b;
    return ((ua.i + 0x8000u) >> 16) | ((ub.i + 0x8000u) & 0xffff0000u);
}

// async 16B global -> LDS (wave-uniform LDS base; HW adds lane*16)
__device__ __forceinline__ void gload16(const void* g, void* l) {
    __builtin_amdgcn_global_load_lds(
        (const __attribute__((address_space(1))) unsigned int*)g,
        (__attribute__((address_space(3))) unsigned int*)l, 16, 0, 0);
}

// ---------- fp32 -> bf16 pre-convert (x, Wz, Wh), 8 floats/thread ----------
__global__ __launch_bounds__(256) void cvt_bf16(
    const float* __restrict__ x, const float* __restrict__ wz,
    const float* __restrict__ wh, unsigned short* __restrict__ xb,
    unsigned short* __restrict__ zb, unsigned short* __restrict__ hb)
{
    const size_t i = (size_t)blockIdx.x * 256 + threadIdx.x;   // uint4-pair index
    const float4* s; uint4* d; size_t off;
    const size_t xh = X4 / 2, wh4 = W4 / 2;
    if (i < xh)            { s = (const float4*)x;  d = (uint4*)xb; off = i; }
    else if (i < xh + wh4) { s = (const float4*)wz; d = (uint4*)zb; off = i - xh; }
    else                   { s = (const float4*)wh; d = (uint4*)hb; off = i - xh - wh4; }
    const float4 v0 = s[2 * off];
    const float4 v1 = s[2 * off + 1];
    uint4 r;
    r.x = pk2(v0.x, v0.y); r.y = pk2(v0.z, v0.w);
    r.z = pk2(v1.x, v1.y); r.w = pk2(v1.z, v1.w);
    d[off] = r;
}

// ---------- MFMA GEMM + activation epilogue + fused chunk-carry (phase A) ----------
__global__ __launch_bounds__(256, 2) void gemm_act_mfma(
    const unsigned short* __restrict__ xb, const unsigned short* __restrict__ zb,
    const unsigned short* __restrict__ hb, const float* __restrict__ bz,
    const float* __restrict__ bh, unsigned int* __restrict__ ab,
    float* __restrict__ carryA, float* __restrict__ carryB)
{
    __shared__ unsigned short xs[BM * BK];   // 8 KB, 64 B rows, NO pad
    __shared__ unsigned short zs[BN * BK];   // 4 KB
    __shared__ unsigned short hs[BN * BK];   // 4 KB

    const int tid  = threadIdx.x;
    const int wid  = tid >> 6;
    const int lane = tid & 63;
    const int lm   = lane & 15;
    const int q    = lane >> 4;
    const int wy   = wid >> 1;   // m-half (64 rows)
    const int wx   = wid & 1;    // n-half (32 cols)

    const int m0 = blockIdx.y * BM;
    const int n0 = blockIdx.x * BN;

    // staging addresses: 64B LDS rows, 16 rows per 1KB issue
    const int slr   = lane >> 2;          // row within issue
    const int sbyte = (lane & 3) << 4;
    const char* gx = (const char*)xb + ((size_t)(m0 + wid * 32 + slr) * DIN) * 2 + sbyte;
    const char* gz = (const char*)zb + ((size_t)(n0 + wid * 16 + slr) * DIN) * 2 + sbyte;
    const char* gh = (const char*)hb + ((size_t)(n0 + wid * 16 + slr) * DIN) * 2 + sbyte;
    char* xl = (char*)xs + wid * 2048;
    char* zl = (char*)zs + wid * 1024;
    char* hl = (char*)hs + wid * 1024;

    f32x4 acc1[4][2], acc2[4][2];
#pragma unroll
    for (int mt = 0; mt < 4; ++mt)
#pragma unroll
        for (int nt = 0; nt < 2; ++nt) {
            acc1[mt][nt] = (f32x4){0.f, 0.f, 0.f, 0.f};
            acc2[mt][nt] = (f32x4){0.f, 0.f, 0.f, 0.f};
        }

    for (int k0 = 0; k0 < DIN; k0 += BK) {
        const size_t kb = (size_t)k0 * 2;
        __syncthreads();                         // prev tile consumed
        gload16(gx + kb,          xl);
        gload16(gx + kb + 32768,  xl + 1024);    // +16 rows
        gload16(gz + kb,          zl);
        gload16(gh + kb,          hl);
        __syncthreads();                         // drain; tile visible

        bf16x8 a[4];
#pragma unroll
        for (int mt = 0; mt < 4; ++mt)
            a[mt] = *(const bf16x8*)((const char*)xs + ((wy * 64 + mt * 16 + lm) * 64 + q * 16));
#pragma unroll
        for (int nt = 0; nt < 2; ++nt) {
            const int bo = (wx * 32 + nt * 16 + lm) * 64 + q * 16;
            const bf16x8 vz = *(const bf16x8*)((const char*)zs + bo);
            const bf16x8 vh = *(const bf16x8*)((const char*)hs + bo);
#pragma unroll
            for (int mt = 0; mt < 4; ++mt) {
                acc1[mt][nt] = __builtin_amdgcn_mfma_f32_16x16x32_bf16(a[mt], vz, acc1[mt][nt], 0, 0, 0);
                acc2[mt][nt] = __builtin_amdgcn_mfma_f32_16x16x32_bf16(a[mt], vh, acc2[mt][nt], 0, 0, 0);
            }
        }
    }

    // ---- epilogue: activations, ab pack, fused per-32-row chunk carries ----
    // C layout: col = lm, row = q*4 + r
    const int bi    = m0 >> 12;
    const int cbase = ((m0 & 4095) >> 5) + wy * 2;

#pragma unroll
    for (int nt = 0; nt < 2; ++nt) {
        const int col = n0 + wx * 32 + nt * 16 + lm;
        const float bzv = bz[col];
        const float bhv = bh[col];
#pragma unroll
        for (int half = 0; half < 2; ++half) {
            float CA = 1.f, CB = 0.f;
#pragma unroll
            for (int mi = 0; mi < 2; ++mi) {
                const int mt = half * 2 + mi;
                const int row0 = m0 + wy * 64 + mt * 16 + q * 4;
                float A = 1.f, B = 0.f;
#pragma unroll
                for (int r = 0; r < 4; ++r) {
                    const float kpre = acc1[mt][nt][r] + bzv;
                    const float hpre = acc2[mt][nt][r] + bhv;
                    const float ez   = __expf(-kpre);
                    const float zv   = 1.0f / (1.0f + ez);   // sigmoid(k)
                    const float av   = ez * zv;              // sigmoid(-k)
                    const float g    = (hpre >= 0.f) ? (hpre + 0.5f)
                                                     : (1.0f / (1.0f + __expf(-hpre)));
                    const float bv   = zv * g;
                    ab[(size_t)(row0 + r) * HDIM + col] = pk2(av, bv);
                    A = av * A;                  // compose ascending t
                    B = fmaf(av, B, bv);
                }
                // compose across q (rows q*4..q*4+3 -> full 16-row segment)
                float A2 = __shfl_xor(A, 16, 64);
                float B2 = __shfl_xor(B, 16, 64);
                B = (q & 1) ? fmaf(A, B2, B) : fmaf(A2, B, B2);
                A = A * A2;
                A2 = __shfl_xor(A, 32, 64);
                B2 = __shfl_xor(B, 32, 64);
                B = (q & 2) ? fmaf(A, B2, B) : fmaf(A2, B, B2);
                A = A * A2;
                // chunk compose across mt (ascending)
                CB = fmaf(A, CB, B);
                CA = A * CA;
            }
            if (q == 0) {
                const int cseq = cbase + half;
                const size_t ci = ((size_t)(cseq * BSZ + bi)) * HDIM + col;
                carryA[ci] = CA;
                carryB[ci] = CB;
            }
        }
    }
}

// ---------- Phase B: sequential scan over chunk carries ----------
__global__ __launch_bounds__(256) void scan_phaseB(
    const float* __restrict__ h0, const float* __restrict__ carryA,
    const float* __restrict__ carryB, float* __restrict__ hin)
{
    const int h  = blockIdx.x * 256 + threadIdx.x;
    const int bi = blockIdx.y;
    const float v = h0[(size_t)bi * HDIM + h];
    float hr = (v >= 0.0f) ? (v + 0.5f) : (1.0f / (1.0f + __expf(-v)));
    for (int c = 0; c < NCH; ++c) {
        const size_t ci = ((size_t)c * BSZ + bi) * HDIM + h;
        hin[ci] = hr;
        hr = fmaf(carryA[ci], hr, carryB[ci]);
    }
}

// ---------- Phase C: replay chunk with known h_in, 4 channels/thread ----------
__global__ __launch_bounds__(256) void scan_phaseC(
    const unsigned int* __restrict__ ab, const float* __restrict__ hin,
    float* __restrict__ out)
{
    const int c  = blockIdx.x;     // 0..127
    const int bi = blockIdx.y;     // 0..3
    const int h  = threadIdx.x * 4;
    size_t idx = ((size_t)bi * SEQ + (size_t)c * CL) * HDIM + h;
    const size_t ci = ((size_t)c * BSZ + bi) * HDIM + h;
    float4 hr = *(const float4*)&hin[ci];
#pragma unroll 4
    for (int t = 0; t < CL; ++t) {
        const uint4 v = *(const uint4*)&ab[idx];
        hr.x = fmaf(bf2f(v.x & 0xffffu), hr.x, bf2f(v.x >> 16));
        hr.y = fmaf(bf2f(v.y & 0xffffu), hr.y, bf2f(v.y >> 16));
        hr.z = fmaf(bf2f(v.z & 0xffffu), hr.z, bf2f(v.z >> 16));
        hr.w = fmaf(bf2f(v.w & 0xffffu), hr.w, bf2f(v.w >> 16));
        *(float4*)&out[idx] = hr;
        idx += HDIM;
    }
}

extern "C" void kernel_launch(void* const* d_in, const int* in_sizes, int n_in,
                              void* d_out, int out_size, void* d_ws, size_t ws_size,
                              hipStream_t stream)
{
    const float* x  = (const float*)d_in[0];
    const float* h0 = (const float*)d_in[1];
    const float* Wz = (const float*)d_in[2];
    const float* bz = (const float*)d_in[3];
    const float* Wh = (const float*)d_in[4];
    const float* bh = (const float*)d_in[5];
    float* out = (float*)d_out;

    // workspace (~111 MB; ws_size known >= 137 MB)
    unsigned int*   ab  = (unsigned int*)d_ws;             // NELE
    unsigned short* xbf = (unsigned short*)(ab + NELE);    // NX
    unsigned short* zbf = xbf + NX;                        // NW
    unsigned short* hbf = zbf + NW;                        // NW
    float* carryA = (float*)(hbf + NW);                    // NCH*BSZ*HDIM
    float* carryB = carryA + (size_t)NCH * BSZ * HDIM;
    float* hin    = carryB + (size_t)NCH * BSZ * HDIM;

    const int cvtBlocks = (int)((X4 + 2 * W4) / 2 / 256);  // 9216
    cvt_bf16<<<cvtBlocks, 256, 0, stream>>>(x, Wz, Wh, xbf, zbf, hbf);

    dim3 gGrid(HDIM / BN, MTOT / BM);                      // (16, 128)
    gemm_act_mfma<<<gGrid, 256, 0, stream>>>(xbf, zbf, hbf, bz, bh, ab, carryA, carryB);

    dim3 bGrid(HDIM / 256, BSZ);                           // (4, 4)
    scan_phaseB<<<bGrid, 256, 0, stream>>>(h0, carryA, carryB, hin);

    dim3 cGrid(NCH, BSZ);                                  // (128, 4)
    scan_phaseC<<<cGrid, 256, 0, stream>>>(ab, hin, out);
}